// Round 1
// baseline (27.388 us; speedup 1.0000x reference)
//
#include <hip/hip_runtime.h>

#define NS 7
#define NC 256
#define NH 64
#define NW 64
#define NR 128

__global__ __launch_bounds__(256) void roi_pool_kernel(
    const float* __restrict__ f,
    const int* __restrict__ rois,
    float* __restrict__ out,
    int total)
{
    int t = blockIdx.x * blockDim.x + threadIdx.x;
    if (t >= total) return;

    int bin = t % (NS * NS);
    int tc  = t / (NS * NS);
    int c   = tc % NC;
    int r   = tc / NC;
    int i   = bin / NS;
    int j   = bin % NS;

    int x1 = rois[4 * r + 0];
    int y1 = rois[4 * r + 1];
    int x2 = rois[4 * r + 2];
    int y2 = rois[4 * r + 3];

    int Lh = x2 - x1 + 1;
    int Lw = y2 - y1 + 1;

    // PyTorch adaptive pooling window: [start, end)
    int rs = x1 + (i * Lh) / NS;
    int re = x1 + ((i + 1) * Lh + NS - 1) / NS;
    int cs = y1 + (j * Lw) / NS;
    int ce = y1 + ((j + 1) * Lw + NS - 1) / NS;

    const float* fc = f + (size_t)c * (NH * NW);

    float m = -3.402823466e+38f;  // -FLT_MAX == jnp.finfo(float32).min
    for (int h = rs; h < re; ++h) {
        const float* row = fc + h * NW;
        for (int w = cs; w < ce; ++w) {
            m = fmaxf(m, row[w]);
        }
    }

    // out[(r, c, bin)] with bin = i*7 + j, flattened == t
    out[t] = m;
}

extern "C" void kernel_launch(void* const* d_in, const int* in_sizes, int n_in,
                              void* d_out, int out_size, void* d_ws, size_t ws_size,
                              hipStream_t stream)
{
    const float* feature_map = (const float*)d_in[0];
    const int*   rois        = (const int*)d_in[1];
    float*       out         = (float*)d_out;

    int total = NR * NC * NS * NS;  // 1,605,632
    int block = 256;
    int grid  = (total + block - 1) / block;

    roi_pool_kernel<<<grid, block, 0, stream>>>(feature_map, rois, out, total);
}